// Round 4
// baseline (263.959 us; speedup 1.0000x reference)
//
#include <hip/hip_runtime.h>
#include <stdint.h>

#define NB 8
#define CI 128
#define CO 256
#define KS 7
#define LL 16384
#define CK (CI * KS)   // 896

typedef _Float16 half8 __attribute__((ext_vector_type(8)));
typedef _Float16 half2v __attribute__((ext_vector_type(2)));
typedef float floatx4 __attribute__((ext_vector_type(4)));
typedef uint32_t uintx4 __attribute__((ext_vector_type(4)));

__device__ __forceinline__ void load16_to_lds(const void* g, void* l) {
    __builtin_amdgcn_global_load_lds(
        (const __attribute__((address_space(1))) void*)g,
        (__attribute__((address_space(3))) void*)l, 16, 0, 0);
}

// ---------- fused prepass ----------
// blocks [0, NB*256):      x (NB,CI,LL) f32 -> xT (NB,LL,CI) f16, 64l x 128c tiles
// blocks [NB*256, +CO):    w (CO,CI,KS) f32 -> wT (CO, KS*CI) f16 (ck-order k*128+c)
// block  NB*256+CO:        zero row (128 halfs) appended to wT
__global__ __launch_bounds__(256) void prep(const float* __restrict__ x,
                                            const float* __restrict__ w,
                                            _Float16* __restrict__ xT,
                                            _Float16* __restrict__ wT) {
    __shared__ uint32_t smem[64][65];   // 16.6 KB (w path reuses as float[896])
    const int b = blockIdx.x;
    const int t = threadIdx.x;

    if (b < NB * 256) {
        const int n  = b >> 8;
        const int l0 = (b & 255) * 64;
        const float* xs = x + (size_t)n * CI * LL + l0;
        const int l4  = (t & 15) * 4;
        const int cpr = t >> 4;
        #pragma unroll
        for (int p = 0; p < 4; ++p) {
            const int cp = cpr + p * 16;   // c-pair 0..63
            const float4 a4 = *(const float4*)(xs + (size_t)(2 * cp) * LL + l4);
            const float4 b4 = *(const float4*)(xs + (size_t)(2 * cp + 1) * LL + l4);
            half2v h;
            h[0] = (_Float16)a4.x; h[1] = (_Float16)b4.x;
            smem[l4 + 0][cp] = __builtin_bit_cast(uint32_t, h);
            h[0] = (_Float16)a4.y; h[1] = (_Float16)b4.y;
            smem[l4 + 1][cp] = __builtin_bit_cast(uint32_t, h);
            h[0] = (_Float16)a4.z; h[1] = (_Float16)b4.z;
            smem[l4 + 2][cp] = __builtin_bit_cast(uint32_t, h);
            h[0] = (_Float16)a4.w; h[1] = (_Float16)b4.w;
            smem[l4 + 3][cp] = __builtin_bit_cast(uint32_t, h);
        }
        __syncthreads();
        const int lw  = t >> 4;
        const int cp0 = (t & 15) * 4;
        _Float16* xd = xT + (size_t)n * LL * CI + (size_t)l0 * CI;
        #pragma unroll
        for (int p = 0; p < 4; ++p) {
            const int l = lw + p * 16;
            uintx4 d;
            d[0] = smem[l][cp0 + 0];
            d[1] = smem[l][cp0 + 1];
            d[2] = smem[l][cp0 + 2];
            d[3] = smem[l][cp0 + 3];
            *(uintx4*)(xd + (size_t)l * CI + cp0 * 2) = d;
        }
    } else if (b < NB * 256 + CO) {
        const int o = b - NB * 256;
        float* lds = (float*)smem;
        for (int i = t; i < CK; i += 256) lds[i] = w[(size_t)o * CK + i];
        __syncthreads();
        if (t < CK / 8) {
            half8 h;
            #pragma unroll
            for (int q = 0; q < 8; ++q) {
                const int dd = t * 8 + q;
                const int k = dd >> 7;
                const int c = dd & 127;
                h[q] = (_Float16)lds[c * KS + k];
            }
            *(half8*)(wT + (size_t)o * CK + t * 8) = h;
        }
    } else {
        if (t < 128) wT[(size_t)CO * CK + t] = (_Float16)0.f;
    }
}

// ---------- MFMA GEMM, BK=32, XOR-swizzled LDS (conflict-free ds_read_b128) ----------
// LDS per operand: 128 rows x 32 halfs. Logical 16B chunk j of row r lives at
// physical chunk j ^ ((r>>1)&3). global_load_lds dest is lane*16 (fixed), so the
// swizzle is applied on the SOURCE side: lane t loads chunk (t&3)^((t>>3)&3).
__global__ __launch_bounds__(256) void iconv_mfma(
    const _Float16* __restrict__ xT,   // (NB, LL, CI)
    const int*      __restrict__ idx,  // (KS, LL), -1 = masked
    const _Float16* __restrict__ wT,   // (CO, CK)
    const float*    __restrict__ bias, // (CO)
    const _Float16* __restrict__ zrow, // 128 halfs of zeros
    float*          __restrict__ out)  // (NB, CO, LL)
{
    __shared__ _Float16 a_lds[128 * 32];   // 8 KB
    __shared__ _Float16 b_lds[128 * 32];   // 8 KB

    const int l0 = blockIdx.x * 128;
    const int o0 = blockIdx.y * 128;
    const int n  = blockIdx.z;
    const int t  = threadIdx.x;
    const int lane = t & 63;
    const int wv = t >> 6;
    const int wo = (wv >> 1) * 64;
    const int wl = (wv & 1) * 64;
    const int m16 = lane & 15;
    // swizzled fragment chunk offset (halfs): (logical j=lane>>4) ^ ((r>>1)&3),
    // row-dependent term reduces to (lane>>1)&3 for all our fragment rows.
    const int sw = ((lane >> 4) ^ ((lane >> 1) & 3)) * 8;

    floatx4 acc[4][4];
    #pragma unroll
    for (int i = 0; i < 4; ++i)
        #pragma unroll
        for (int j = 0; j < 4; ++j) acc[i][j] = (floatx4)0.f;

    const int srow = t >> 2;                      // 0..63
    const int jq   = (t & 3) ^ ((t >> 3) & 3);    // swizzled source chunk

    // prefetch all idx into regs: no dependent loads between barriers
    int iv0[KS], iv1[KS];
    #pragma unroll
    for (int k = 0; k < KS; ++k) {
        iv0[k] = idx[k * LL + l0 + srow];
        iv1[k] = idx[k * LL + l0 + 64 + srow];
    }

    const _Float16* xbase  = xT + (size_t)n * LL * CI;
    const _Float16* abase0 = wT + (size_t)(o0 + srow) * CK + jq * 8;
    const _Float16* abase1 = wT + (size_t)(o0 + 64 + srow) * CK + jq * 8;

    for (int k = 0; k < KS; ++k) {
        const int i0 = iv0[k], i1 = iv1[k];
        const _Float16* b0 = ((i0 >= 0) ? xbase + (size_t)i0 * CI : zrow) + jq * 8;
        const _Float16* b1 = ((i1 >= 0) ? xbase + (size_t)i1 * CI : zrow) + jq * 8;
        const _Float16* a0 = abase0 + k * CI;
        const _Float16* a1 = abase1 + k * CI;
        for (int c0 = 0; c0 < CI; c0 += 32) {
            __syncthreads();
            load16_to_lds(b0 + c0, b_lds + t * 8);
            load16_to_lds(b1 + c0, b_lds + (256 + t) * 8);
            load16_to_lds(a0 + c0, a_lds + t * 8);
            load16_to_lds(a1 + c0, a_lds + (256 + t) * 8);
            __syncthreads();

            half8 af[4], bf[4];
            #pragma unroll
            for (int mf = 0; mf < 4; ++mf)
                af[mf] = *(const half8*)(a_lds + (wo + mf * 16 + m16) * 32 + sw);
            #pragma unroll
            for (int nf = 0; nf < 4; ++nf)
                bf[nf] = *(const half8*)(b_lds + (wl + nf * 16 + m16) * 32 + sw);
            #pragma unroll
            for (int mf = 0; mf < 4; ++mf)
                #pragma unroll
                for (int nf = 0; nf < 4; ++nf)
                    acc[mf][nf] = __builtin_amdgcn_mfma_f32_16x16x32_f16(
                        af[mf], bf[nf], acc[mf][nf], 0, 0, 0);
        }
    }

    // epilogue: D[m][n]: m(row)=o=(lane>>4)*4+reg, n(col)=l=lane&15
    const int r4 = (lane >> 4) * 4;
    #pragma unroll
    for (int mf = 0; mf < 4; ++mf) {
        const int obase = o0 + wo + mf * 16 + r4;
        const floatx4 b4 = *(const floatx4*)(bias + obase);
        #pragma unroll
        for (int nf = 0; nf < 4; ++nf) {
            const int l = l0 + wl + nf * 16 + m16;
            float* op = out + ((size_t)n * CO + obase) * LL + l;
            #pragma unroll
            for (int r = 0; r < 4; ++r)
                op[(size_t)r * LL] = acc[mf][nf][r] + b4[r];
        }
    }
}

// ---------- fp32 fallback (only if workspace too small) ----------
__global__ __launch_bounds__(256) void iconv_fallback(
    const float* __restrict__ x, const int* __restrict__ idx,
    const float* __restrict__ w, const float* __restrict__ bias,
    float* __restrict__ out)
{
    __shared__ float col[CI][64];
    const int n  = blockIdx.y;
    const int l0 = blockIdx.x * 64;
    const int t  = threadIdx.x;
    const int ot = t & 63, lt = t >> 6;
    const int j = t >> 2, part = t & 3;
    float acc[4][16];
    #pragma unroll
    for (int oo = 0; oo < 4; ++oo) {
        const float bv = bias[ot * 4 + oo];
        #pragma unroll
        for (int ll = 0; ll < 16; ++ll) acc[oo][ll] = bv;
    }
    for (int k = 0; k < KS; ++k) {
        __syncthreads();
        const int i = idx[k * LL + l0 + j];
        const float* xr = x + (size_t)n * CI * LL;
        for (int q = 0; q < 32; ++q) {
            const int c = part * 32 + q;
            col[c][j] = (i >= 0) ? xr[(size_t)c * LL + i] : 0.f;
        }
        __syncthreads();
        for (int c = 0; c < CI; ++c) {
            const float* bv = &col[c][lt * 16];
            float wv[4];
            #pragma unroll
            for (int oo = 0; oo < 4; ++oo)
                wv[oo] = w[(size_t)(ot * 4 + oo) * CK + c * KS + k];
            #pragma unroll
            for (int oo = 0; oo < 4; ++oo)
                #pragma unroll
                for (int ll = 0; ll < 16; ++ll)
                    acc[oo][ll] += wv[oo] * bv[ll];
        }
    }
    #pragma unroll
    for (int oo = 0; oo < 4; ++oo) {
        float* orow = out + ((size_t)n * CO + (ot * 4 + oo)) * LL + l0 + lt * 16;
        #pragma unroll
        for (int q = 0; q < 16; ++q) orow[q] = acc[oo][q];
    }
}

extern "C" void kernel_launch(void* const* d_in, const int* in_sizes, int n_in,
                              void* d_out, int out_size, void* d_ws, size_t ws_size,
                              hipStream_t stream) {
    const float* x    = (const float*)d_in[0];
    const int*   idx  = (const int*)d_in[1];
    const float* w    = (const float*)d_in[2];
    const float* bias = (const float*)d_in[3];
    float* out = (float*)d_out;

    const size_t xt_bytes = (size_t)NB * LL * CI * sizeof(_Float16);     // 32 MiB
    const size_t wt_elems = (size_t)CO * CK + 128;                       // incl. zero row
    const size_t need = xt_bytes + wt_elems * sizeof(_Float16);

    if (ws_size >= need) {
        _Float16* xT = (_Float16*)d_ws;
        _Float16* wT = (_Float16*)((char*)d_ws + xt_bytes);
        const _Float16* zr = wT + (size_t)CO * CK;
        prep<<<dim3(NB * 256 + CO + 1), 256, 0, stream>>>(x, w, xT, wT);
        iconv_mfma<<<dim3(LL / 128, CO / 128, NB), 256, 0, stream>>>(
            xT, idx, wT, bias, zr, out);
    } else {
        iconv_fallback<<<dim3(LL / 64, NB), 256, 0, stream>>>(x, idx, w, bias, out);
    }
}